// Round 5
// baseline (138.808 us; speedup 1.0000x reference)
//
#include <hip/hip_runtime.h>
#include <math.h>

#define N_ROWS 4096
#define DIM    128
#define A_LAB  512
#define INV_TAU 14.285714285714286f
#define C_EXP   20.609929155556620f   // INV_TAU * log2(e)

typedef __attribute__((ext_vector_type(8))) short short8;   // 8 bf16 (4 VGPRs)
typedef __attribute__((ext_vector_type(4))) float f32x4;    // MFMA C/D frag (16x16)
typedef __attribute__((ext_vector_type(4))) int i32x4;      // i8 MFMA A/B frag
typedef __attribute__((ext_vector_type(16))) int i32x16;    // i8 MFMA C/D frag (32x32)

// ---------------- workspace layout (bytes) ----------------
// zbf   u16 [8192*128]   @ 0          (2,097,152)  FRAG-MAJOR (see k_norm_pack)
// labs8 i8  [4096*512]   @ 2,097,152  (2,097,152)  FRAG-MAJOR (see k_norm_pack)
// s     i32 [4096]       @ 4,194,304  (16,384)
// part  f32 [3*4096]     @ 4,210,688  (49,152)     atomically accumulated
// pm    u32 [4096*128]   @ 4,259,840  (2,097,152)  pos-bit mask [row][col word]

__device__ __forceinline__ unsigned short f2bf(float f) {
  unsigned int u = __builtin_bit_cast(unsigned int, f);
  u += 0x7fffu + ((u >> 16) & 1u);            // round-to-nearest-even
  return (unsigned short)(u >> 16);
}

// ------------ kernel 1: L2-normalize (-> bf16, frag-major) + labels -> i8 frag-major ------------
__global__ __launch_bounds__(256) void k_norm_pack(
    const float* __restrict__ z1, const float* __restrict__ z2,
    const int* __restrict__ labels,
    unsigned int* __restrict__ zbf, uint2* __restrict__ labs8,
    int* __restrict__ s, float* __restrict__ part, float* __restrict__ out)
{
  {
    const int idx = blockIdx.x * 256 + threadIdx.x;
    if (idx < 3 * 4096) part[idx] = 0.0f;
    if (idx == 0) out[0] = 0.0f;
  }
  const int wave = threadIdx.x >> 6, lane = threadIdx.x & 63;
  const int r = blockIdx.x * 4 + wave;         // 0..8191
  const float* src = (r < N_ROWS) ? (z1 + (size_t)r * DIM)
                                  : (z2 + (size_t)(r - N_ROWS) * DIM);
  float2 x = ((const float2*)src)[lane];
  float ss = x.x * x.x + x.y * x.y;
  #pragma unroll
  for (int off = 32; off > 0; off >>= 1) ss += __shfl_xor(ss, off);
  const float inv = 1.0f / fmaxf(sqrtf(ss), 1e-12f);
  const unsigned int lo = f2bf(x.x * inv);
  const unsigned int hi = f2bf(x.y * inv);
  {
    // row r, dword index 'lane' (bytes lane*4). unit u=lane>>2, dword p=lane&3.
    const int u = lane >> 2, p = lane & 3;
    const int kf = u >> 2, quad = u & 3;
    const int g = r >> 4;
    zbf[(size_t)(((g * 4 + kf) * 64) + ((r & 15) + (quad << 4))) * 4 + p] = (hi << 16) | lo;
  }

  if (r < N_ROWS) {
    const int4* lp = (const int4*)(labels + (size_t)r * A_LAB);
    const int4 a = lp[2 * lane], b = lp[2 * lane + 1];
    const unsigned int w0 = (unsigned int)(a.x != 0)       | ((unsigned int)(a.y != 0) << 8)
                          | ((unsigned int)(a.z != 0) << 16) | ((unsigned int)(a.w != 0) << 24);
    const unsigned int w1 = (unsigned int)(b.x != 0)       | ((unsigned int)(b.y != 0) << 8)
                          | ((unsigned int)(b.z != 0) << 16) | ((unsigned int)(b.w != 0) << 24);
    uint2 v; v.x = w0; v.y = w1;
    // row r, bytes lane*8..+8: unit ul=lane>>1, half hp=lane&1; ks=ul>>1, h=ul&1
    const int ul = lane >> 1, hp = lane & 1;
    const int ks = ul >> 1, h = ul & 1;
    const int g = r >> 5;
    labs8[(size_t)(((g * 16 + ks) * 64) + ((r & 31) + (h << 5))) * 2 + hp] = v;
    int cnt = __popc(w0) + __popc(w1);         // bytes are 0/1 -> popc == byte sum
    #pragma unroll
    for (int off = 32; off > 0; off >>= 1) cnt += __shfl_xor(cnt, off);
    if (lane == 0) s[r] = cnt;
  }
}

// ------------ kernel 1.5: jaccard -> pos-bit mask, upper-triangle pairs only ------------
// Jaccard is SYMMETRIC: 528 blocks (bi<=bj).  Row-word form via ballot,
// transposed tile via in-register word assembly (both paths absmax-0
// verified R0/R1/R3).  No LDS, no barriers.
__global__ __launch_bounds__(512, 4) void k_jac(
    const unsigned char* __restrict__ labs8, const int* __restrict__ s,
    unsigned int* __restrict__ pm)
{
  // decode blockIdx.x -> (bi, bj), bi<=bj, row-major over upper triangle
  int r = blockIdx.x, row = 0;
  while (r >= 32 - row) { r -= 32 - row; ++row; }
  const int bi = row, bj = row + r;
  const int ibase = bi * 128, jbase = bj * 128;
  const bool diag = (bi == bj);

  const int tid = threadIdx.x;
  const int wave = tid >> 6, lane = tid & 63;
  const char* gl = (const char*)labs8;

  const int jwr = (wave >> 2) * 64;           // rows: waves 0-3 -> 0, 4-7 -> 64
  const int jwc = (wave & 3) * 32;            // cols: 32-wide slice per wave
  const int col32 = lane & 31, h = lane >> 5;

  const int s3i = 3 * s[ibase + jwr + lane];        // this wave's 64 rows
  const int s3j = 3 * s[jbase + jwc + col32];       // this lane's col

  i32x16 jacc[2];
  #pragma unroll
  for (int rt = 0; rt < 2; ++rt)
    #pragma unroll
    for (int e = 0; e < 16; ++e) jacc[rt][e] = 0;

  const int gI = (ibase + jwr) >> 5;          // two 32-row groups: gI, gI+1
  const int gJ = (jbase + jwc) >> 5;          // one 32-row group
  #pragma unroll
  for (int ks = 0; ks < 16; ++ks) {
    i32x4 a[2], b;
    #pragma unroll
    for (int rt = 0; rt < 2; ++rt)
      a[rt] = *(const i32x4*)(gl + (size_t)(((gI + rt) * 16 + ks) * 64 + lane) * 16);
    b = *(const i32x4*)(gl + (size_t)((gJ * 16 + ks) * 64 + lane) * 16);
    #pragma unroll
    for (int rt = 0; rt < 2; ++rt)
      jacc[rt] = __builtin_amdgcn_mfma_i32_32x32x32_i8(a[rt], b, jacc[rt], 0, 0, 0);
  }

  // epilogue: threshold -> ballot row-words at [i][jword], transpose words at [j][iword]
  const int wl = wave & 3;
  const int jw0 = (jbase >> 5);
  unsigned int tw0 = 0, tw1 = 0;
  #pragma unroll
  for (int rt = 0; rt < 2; ++rt)
    #pragma unroll
    for (int reg = 0; reg < 16; ++reg) {
      const int r0 = (reg & 3) + 8 * (reg >> 2);
      const int si = __shfl(s3i, rt * 32 + r0 + 4 * h);
      const bool pred = 13 * jacc[rt][reg] >= si + s3j;
      const unsigned long long bal = __ballot(pred);
      const int lr = jwr + rt * 32 + r0;
      if (lane == 0)      pm[(size_t)(ibase + lr) * 128 + jw0 + wl]       = (unsigned int)bal;
      else if (lane == 1) pm[(size_t)(ibase + lr + 4) * 128 + jw0 + wl]   = (unsigned int)(bal >> 32);
      const unsigned int pb = ((unsigned int)pred) << (r0 + 4 * h);
      if (rt == 0) tw0 |= pb; else tw1 |= pb;
    }
  if (!diag) {
    // lanes h=0/h=1 hold complementary bit positions of the same 32-row word
    tw0 |= __shfl_xor(tw0, 32);
    tw1 |= __shfl_xor(tw1, 32);
    const size_t trow = (size_t)(jbase + jwc + col32) * 128 + (ibase >> 5) + (jwr >> 5);
    if (h == 0) pm[trow]     = tw0;
    else        pm[trow + 1] = tw1;
  }
}

// ------------ kernel 2: similarity + masked-softmax, 256 threads ------------
// Block = 128 anchors (blockIdx.y) x 128 cols of ONE half (blockIdx.x 0..63;
// half = cb>>5).  4 waves, each wave 32 anchor rows: two 16-row A-frag sets
// SHARE every B-fragment -> LDS-read volume per output halved vs R3 (32
// ds_read_b128 per 32x128 tile).  Single 32 KB contiguous stage + ONE
// __syncthreads.  Epilogue fused per-nt (only 8 acc f32 live) to keep
// VGPR ~140 under __launch_bounds__(256,3) (R1 lesson: no spills).
// Self-exclusion lives only in blocks cb==ib (32), aug-pair only in blocks
// cb==ib+32 (32); generic blocks use per-half popc for P (no x2).
__global__ __launch_bounds__(256, 3) void k_fused(
    const unsigned int* __restrict__ pm,
    const unsigned short* __restrict__ zbf, float* __restrict__ part)
{
  __shared__ __align__(16) char bpanel[32768];   // this block's 128-col B panel
  const int tid = threadIdx.x;
  const int cb = blockIdx.x;                 // 0..63 col tile over [z1n;z2n]
  const int ib = blockIdx.y;                 // 0..31 anchor tile
  const int ibase = ib * 128;
  const int wave = tid >> 6, lane = tid & 63;
  const int col = lane & 15, quad = lane >> 4;
  const int wbase = wave * 32;               // 32 anchor rows per wave
  const char* gz = (const char*)zbf;

  const bool selfd = (cb == ib);             // half-0 block containing self cols
  const bool augd  = (cb == ib + 32);        // half-1 block containing aug cols
  const bool special = selfd || augd;

  // stage B panel: zbf frag-groups for global rows [cb*128, +128): 32 KB contiguous
  {
    const char* srcp = gz + (size_t)cb * 32768;
    #pragma unroll
    for (int q = 0; q < 8; ++q)
      *(uint4*)(bpanel + (size_t)(q * 256 + tid) * 16) =
          *(const uint4*)(srcp + (size_t)(q * 256 + tid) * 16);
  }

  // A fragments for this wave's 32 rows (2 row-frags x 4 k-frags)
  short8 afr[2][4];
  #pragma unroll
  for (int rt = 0; rt < 2; ++rt) {
    const int gA = (ibase + wbase + rt * 16) >> 4;
    #pragma unroll
    for (int kf = 0; kf < 4; ++kf)
      afr[rt][kf] = *(const short8*)(gz + (size_t)((gA * 4 + kf) * 64 + lane) * 16);
  }

  // mask words: row = wbase + rt*16 + quad*4 + reg, word window (cb&31)*4
  uint4 pw[2][4];
  #pragma unroll
  for (int rt = 0; rt < 2; ++rt)
    #pragma unroll
    for (int reg = 0; reg < 4; ++reg)
      pw[rt][reg] = *(const uint4*)&pm[
          (size_t)(ibase + wbase + rt * 16 + quad * 4 + reg) * 128 + (cb & 31) * 4];

  float lacc[2][4], Sacc[2][4], Pcnt[2][4];
  #pragma unroll
  for (int rt = 0; rt < 2; ++rt)
    #pragma unroll
    for (int reg = 0; reg < 4; ++reg) { lacc[rt][reg] = 0; Sacc[rt][reg] = 0; Pcnt[rt][reg] = 0; }

  __syncthreads();   // panel ready (the only barrier)

  #pragma unroll
  for (int nt = 0; nt < 8; ++nt) {
    short8 bfr[4];
    #pragma unroll
    for (int kf = 0; kf < 4; ++kf)
      bfr[kf] = *(const short8*)(bpanel + (size_t)((nt * 4 + kf) * 64 + lane) * 16);
    f32x4 acc[2];
    acc[0] = (f32x4){0, 0, 0, 0};
    acc[1] = (f32x4){0, 0, 0, 0};
    #pragma unroll
    for (int kf = 0; kf < 4; ++kf) {
      acc[0] = __builtin_amdgcn_mfma_f32_16x16x32_bf16(afr[0][kf], bfr[kf], acc[0], 0, 0, 0);
      acc[1] = __builtin_amdgcn_mfma_f32_16x16x32_bf16(afr[1][kf], bfr[kf], acc[1], 0, 0, 0);
    }

    if (!special) {
      const int bitpos = (nt & 1) * 16 + col;
      #pragma unroll
      for (int rt = 0; rt < 2; ++rt)
        #pragma unroll
        for (int reg = 0; reg < 4; ++reg) {
          const unsigned int w = ((const unsigned int*)&pw[rt][reg])[nt >> 1];
          const float d = acc[rt][reg];
          lacc[rt][reg] += exp2f(fmaf(d, C_EXP, -C_EXP));
          if ((w >> bitpos) & 1) Sacc[rt][reg] += d;
        }
    } else {
      const int joff = nt * 16 + col;        // local col 0..127
      const int bitpos = joff & 31;
      #pragma unroll
      for (int rt = 0; rt < 2; ++rt)
        #pragma unroll
        for (int reg = 0; reg < 4; ++reg) {
          const int iloc = wbase + rt * 16 + quad * 4 + reg;   // local row 0..127
          const unsigned int w = ((const unsigned int*)&pw[rt][reg])[nt >> 1];
          const float d = acc[rt][reg];
          const bool bit = (w >> bitpos) & 1;
          const bool hit = (joff == iloc);   // self col (half0) or aug col (half1)
          const bool self = selfd && hit;
          const bool pos = selfd ? (bit && !self) : (bit || hit);
          const float e = exp2f(fmaf(d, C_EXP, -C_EXP));
          if (!self) lacc[rt][reg] += e;
          if (pos) { Sacc[rt][reg] += d; Pcnt[rt][reg] += 1.0f; }
        }
    }
  }

  // ---- reduce across the 16 col-lanes, atomically accumulate per-anchor ----
  #pragma unroll
  for (int rt = 0; rt < 2; ++rt)
    #pragma unroll
    for (int reg = 0; reg < 4; ++reg) {
      float l = lacc[rt][reg], S = Sacc[rt][reg], P = Pcnt[rt][reg];
      #pragma unroll
      for (int m = 1; m < 16; m <<= 1) {
        l += __shfl_xor(l, m);
        S += __shfl_xor(S, m);
        if (special) P += __shfl_xor(P, m);
      }
      if (col == 0) {
        const int i = ibase + wbase + rt * 16 + quad * 4 + reg;
        if (!special) {
          const uint4 w = pw[rt][reg];
          P = (float)(__popc(w.x) + __popc(w.y) + __popc(w.z) + __popc(w.w));
        }
        atomicAdd(&part[i], l);
        atomicAdd(&part[4096 + i], S);
        atomicAdd(&part[8192 + i], P);
      }
    }
}

// ---------------- kernel 3: per-anchor loss + atomic final reduce ----------------
__global__ __launch_bounds__(128) void k_loss(
    const float* __restrict__ part, float* __restrict__ out)
{
  const int a = blockIdx.x * 128 + threadIdx.x;   // 0..4095
  const float l = part[a];
  const float S = part[4096 + a];
  const float P = part[8192 + a];
  const float np = fmaxf(P, 1.0f);
  float v = INV_TAU + logf(l + 1e-8f) - (S * INV_TAU) / np;
  #pragma unroll
  for (int off = 32; off > 0; off >>= 1) v += __shfl_xor(v, off);
  __shared__ float ws2[2];
  const int wave = threadIdx.x >> 6, lane = threadIdx.x & 63;
  if (lane == 0) ws2[wave] = v;
  __syncthreads();
  if (threadIdx.x == 0) atomicAdd(out, (ws2[0] + ws2[1]) * (1.0f / (float)N_ROWS));
}

extern "C" void kernel_launch(void* const* d_in, const int* in_sizes, int n_in,
                              void* d_out, int out_size, void* d_ws, size_t ws_size,
                              hipStream_t stream) {
  const float* z1 = (const float*)d_in[0];
  const float* z2 = (const float*)d_in[1];
  const int* labels = (const int*)d_in[2];
  float* out = (float*)d_out;
  char* ws = (char*)d_ws;

  unsigned int* zbf    = (unsigned int*)(ws);
  uint2* labs8         = (uint2*)(ws + 2097152);
  int* s               = (int*)(ws + 4194304);
  float* part          = (float*)(ws + 4210688);
  unsigned int* pm     = (unsigned int*)(ws + 4259840);

  hipLaunchKernelGGL(k_norm_pack, dim3(2048), dim3(256), 0, stream,
                     z1, z2, labels, zbf, labs8, s, part, out);
  hipLaunchKernelGGL(k_jac, dim3(528), dim3(512), 0, stream,
                     (const unsigned char*)labs8, s, pm);
  hipLaunchKernelGGL(k_fused, dim3(64, 32), dim3(256), 0, stream,
                     pm, (const unsigned short*)zbf, part);
  hipLaunchKernelGGL(k_loss, dim3(32), dim3(128), 0, stream, part, out);
}

// Round 6
// 104.451 us; speedup vs baseline: 1.3289x; 1.3289x over previous
//
#include <hip/hip_runtime.h>
#include <math.h>

#define N_ROWS 4096
#define DIM    128
#define A_LAB  512
#define INV_TAU 14.285714285714286f
#define C_EXP   20.609929155556620f   // INV_TAU * log2(e)

typedef __attribute__((ext_vector_type(8))) short short8;   // 8 bf16 (4 VGPRs)
typedef __attribute__((ext_vector_type(4))) float f32x4;    // MFMA C/D frag (16x16)
typedef __attribute__((ext_vector_type(4))) int i32x4;      // i8 MFMA A/B frag
typedef __attribute__((ext_vector_type(16))) int i32x16;    // i8 MFMA C/D frag (32x32)

// ---------------- workspace layout (bytes) ----------------
// zbf   u16 [8192*128]   @ 0          (2,097,152)  FRAG-MAJOR (see k_norm_pack)
// labs8 i8  [4096*512]   @ 2,097,152  (2,097,152)  FRAG-MAJOR (see k_norm_pack)
// s     i32 [4096]       @ 4,194,304  (16,384)
// part  f32 [3*4096]     @ 4,210,688  (49,152)     atomically accumulated
// pm    u32 [4096*128]   @ 4,259,840  (2,097,152)  pos-bit mask [row][col word]

__device__ __forceinline__ unsigned short f2bf(float f) {
  unsigned int u = __builtin_bit_cast(unsigned int, f);
  u += 0x7fffu + ((u >> 16) & 1u);            // round-to-nearest-even
  return (unsigned short)(u >> 16);
}

// ------------ kernel 1: L2-normalize (-> bf16, frag-major) + labels -> i8 frag-major ------------
__global__ __launch_bounds__(256) void k_norm_pack(
    const float* __restrict__ z1, const float* __restrict__ z2,
    const int* __restrict__ labels,
    unsigned int* __restrict__ zbf, uint2* __restrict__ labs8,
    int* __restrict__ s, float* __restrict__ part, float* __restrict__ out)
{
  {
    const int idx = blockIdx.x * 256 + threadIdx.x;
    if (idx < 3 * 4096) part[idx] = 0.0f;
    if (idx == 0) out[0] = 0.0f;
  }
  const int wave = threadIdx.x >> 6, lane = threadIdx.x & 63;
  const int r = blockIdx.x * 4 + wave;         // 0..8191
  const float* src = (r < N_ROWS) ? (z1 + (size_t)r * DIM)
                                  : (z2 + (size_t)(r - N_ROWS) * DIM);
  float2 x = ((const float2*)src)[lane];
  float ss = x.x * x.x + x.y * x.y;
  #pragma unroll
  for (int off = 32; off > 0; off >>= 1) ss += __shfl_xor(ss, off);
  const float inv = 1.0f / fmaxf(sqrtf(ss), 1e-12f);
  const unsigned int lo = f2bf(x.x * inv);
  const unsigned int hi = f2bf(x.y * inv);
  {
    // row r, dword index 'lane' (bytes lane*4). unit u=lane>>2, dword p=lane&3.
    const int u = lane >> 2, p = lane & 3;
    const int kf = u >> 2, quad = u & 3;
    const int g = r >> 4;
    zbf[(size_t)(((g * 4 + kf) * 64) + ((r & 15) + (quad << 4))) * 4 + p] = (hi << 16) | lo;
  }

  if (r < N_ROWS) {
    const int4* lp = (const int4*)(labels + (size_t)r * A_LAB);
    const int4 a = lp[2 * lane], b = lp[2 * lane + 1];
    const unsigned int w0 = (unsigned int)(a.x != 0)       | ((unsigned int)(a.y != 0) << 8)
                          | ((unsigned int)(a.z != 0) << 16) | ((unsigned int)(a.w != 0) << 24);
    const unsigned int w1 = (unsigned int)(b.x != 0)       | ((unsigned int)(b.y != 0) << 8)
                          | ((unsigned int)(b.z != 0) << 16) | ((unsigned int)(b.w != 0) << 24);
    uint2 v; v.x = w0; v.y = w1;
    // row r, bytes lane*8..+8: unit ul=lane>>1, half hp=lane&1; ks=ul>>1, h=ul&1
    const int ul = lane >> 1, hp = lane & 1;
    const int ks = ul >> 1, h = ul & 1;
    const int g = r >> 5;
    labs8[(size_t)(((g * 16 + ks) * 64) + ((r & 31) + (h << 5))) * 2 + hp] = v;
    int cnt = __popc(w0) + __popc(w1);         // bytes are 0/1 -> popc == byte sum
    #pragma unroll
    for (int off = 32; off > 0; off >>= 1) cnt += __shfl_xor(cnt, off);
    if (lane == 0) s[r] = cnt;
  }
}

// ------------ kernel 1.5: jaccard -> pos-bit mask, 64-row-tile upper-tri pairs ------------
// Same math/paths as the R3 k_jac (ballot row-words + in-register transpose,
// absmax-0 verified) but on 64x64 tiles: 2080 blocks x 128 threads (2 waves,
// each 64 rows x 32 cols) instead of 528 x 512.  4x the blocks/CU (2.06 ->
// 8.1), ~16 waves/CU co-resident, no LDS: restores latency hiding for the
// serial 16-kstep load->MFMA chain that made the 528-block version ~23 us.
__global__ __launch_bounds__(128, 4) void k_jac(
    const unsigned char* __restrict__ labs8, const int* __restrict__ s,
    unsigned int* __restrict__ pm)
{
  // decode blockIdx.x -> (bi, bj), bi<=bj over 64 row-tiles of 64 rows
  int r = blockIdx.x, row = 0;
  while (r >= 64 - row) { r -= 64 - row; ++row; }
  const int bi = row, bj = row + r;
  const int ibase = bi * 64, jbase = bj * 64;
  const bool diag = (bi == bj);

  const int tid = threadIdx.x;
  const int wave = tid >> 6, lane = tid & 63;   // wave 0/1: cols w*32..+32
  const char* gl = (const char*)labs8;

  const int col32 = lane & 31, h = lane >> 5;

  const int s3i = 3 * s[ibase + lane];                    // tile's 64 rows
  const int s3j = 3 * s[jbase + wave * 32 + col32];       // this lane's col

  i32x16 jacc[2];
  #pragma unroll
  for (int rt = 0; rt < 2; ++rt)
    #pragma unroll
    for (int e = 0; e < 16; ++e) jacc[rt][e] = 0;

  const int gI = ibase >> 5;                  // two 32-row groups: gI, gI+1
  const int gJ = (jbase >> 5) + wave;         // this wave's col group
  #pragma unroll
  for (int ks = 0; ks < 16; ++ks) {
    i32x4 a[2], b;
    #pragma unroll
    for (int rt = 0; rt < 2; ++rt)
      a[rt] = *(const i32x4*)(gl + (size_t)(((gI + rt) * 16 + ks) * 64 + lane) * 16);
    b = *(const i32x4*)(gl + (size_t)((gJ * 16 + ks) * 64 + lane) * 16);
    #pragma unroll
    for (int rt = 0; rt < 2; ++rt)
      jacc[rt] = __builtin_amdgcn_mfma_i32_32x32x32_i8(a[rt], b, jacc[rt], 0, 0, 0);
  }

  // epilogue: threshold -> ballot row-words at [i][jword], transpose words at [j][iword]
  const int jw0 = (jbase >> 5) + wave;
  unsigned int tw0 = 0, tw1 = 0;
  #pragma unroll
  for (int rt = 0; rt < 2; ++rt)
    #pragma unroll
    for (int reg = 0; reg < 16; ++reg) {
      const int r0 = (reg & 3) + 8 * (reg >> 2);
      const int si = __shfl(s3i, rt * 32 + r0 + 4 * h);
      const bool pred = 13 * jacc[rt][reg] >= si + s3j;
      const unsigned long long bal = __ballot(pred);
      const int lr = rt * 32 + r0;            // local row (low half; +4 for high)
      if (lane == 0)      pm[(size_t)(ibase + lr) * 128 + jw0]       = (unsigned int)bal;
      else if (lane == 1) pm[(size_t)(ibase + lr + 4) * 128 + jw0]   = (unsigned int)(bal >> 32);
      const unsigned int pb = ((unsigned int)pred) << (r0 + 4 * h);
      if (rt == 0) tw0 |= pb; else tw1 |= pb;
    }
  if (!diag) {
    // lanes h=0/h=1 hold complementary bit positions of the same 32-row word
    tw0 |= __shfl_xor(tw0, 32);
    tw1 |= __shfl_xor(tw1, 32);
    const size_t trow = (size_t)(jbase + wave * 32 + col32) * 128 + (ibase >> 5);
    if (h == 0) pm[trow]     = tw0;
    else        pm[trow + 1] = tw1;
  }
}

// ------------ kernel 2: similarity + masked-softmax (S phase only), 512 threads ------------
// EXACT R3 structure (measured-best S): mask words from pm[] (one uint4 per
// anchor row), B panels LDS-staged per half (contiguous 32 KB memcpy,
// conflict-free lane-contiguous ds_read_b128 readback).  LDS 32.8 KB ->
// 4 blocks/CU, 32 waves/CU at VGPR<=64.  R5 lesson: 256t/2048-block split
// halved co-residency and doubled atomics -> 58 us; this shape is ~26-28.
__global__ __launch_bounds__(512, 4) void k_fused(
    const unsigned int* __restrict__ pm,
    const unsigned short* __restrict__ zbf, float* __restrict__ part)
{
  __shared__ __align__(16) char bpanel[32768];       // one half's S-phase B panel
  const int tid = threadIdx.x;
  const int ibase = blockIdx.x * 128, jbase = blockIdx.y * 128;
  const int wave = tid >> 6, lane = tid & 63;
  const bool diag = (ibase == jbase);
  const char* gz = (const char*)zbf;

  const int col = lane & 15, quad = lane >> 4;
  const int srow = wave * 16;                    // this wave: 16 anchor rows
  const int gA = (ibase + srow) >> 4;

  // mask words for this wave's rows (one uint4 per row from global pm)
  uint4 pw[4];
  #pragma unroll
  for (int reg = 0; reg < 4; ++reg)
    pw[reg] = *(const uint4*)&pm[(size_t)(ibase + srow + quad * 4 + reg) * 128 + (jbase >> 5)];

  // sim A-fragments
  short8 afr[4];
  #pragma unroll
  for (int kf = 0; kf < 4; ++kf)
    afr[kf] = *(const short8*)(gz + (size_t)((gA * 4 + kf) * 64 + lane) * 16);

  // stage half-0 B panel (cols jbase..+128 of z1n): contiguous 32 KB memcpy
  {
    const char* srcp = gz + (size_t)(jbase >> 4) * 4096;
    #pragma unroll
    for (int q = 0; q < 4; ++q)
      *(uint4*)(bpanel + (size_t)(q * 512 + tid) * 16) =
          *(const uint4*)(srcp + (size_t)(q * 512 + tid) * 16);
  }

  __syncthreads();   // half-0 panel ready

  // ---------------- phase S: similarity + softmax partials ----------------
  float lacc[4], Sacc[4], Pcnt[4];
  #pragma unroll
  for (int reg = 0; reg < 4; ++reg) { lacc[reg] = 0; Sacc[reg] = 0; Pcnt[reg] = 0; }

  #pragma unroll
  for (int half = 0; half < 2; ++half) {
    if (half == 1) {
      __syncthreads();   // all waves done reading half-0 panel
      const char* srcp = gz + (size_t)((N_ROWS + jbase) >> 4) * 4096;
      #pragma unroll
      for (int q = 0; q < 4; ++q)
        *(uint4*)(bpanel + (size_t)(q * 512 + tid) * 16) =
            *(const uint4*)(srcp + (size_t)(q * 512 + tid) * 16);
      __syncthreads();   // half-1 panel ready
    }

    f32x4 acc[8];
    #pragma unroll
    for (int nt = 0; nt < 8; ++nt) acc[nt] = (f32x4){0, 0, 0, 0};

    #pragma unroll
    for (int nt = 0; nt < 8; ++nt) {
      short8 bfr[4];
      #pragma unroll
      for (int kf = 0; kf < 4; ++kf)
        bfr[kf] = *(const short8*)(bpanel + (size_t)((nt * 4 + kf) * 64 + lane) * 16);
      #pragma unroll
      for (int kf = 0; kf < 4; ++kf)
        acc[nt] = __builtin_amdgcn_mfma_f32_16x16x32_bf16(afr[kf], bfr[kf], acc[nt], 0, 0, 0);
    }

    if (!diag) {
      // slim: same mask both halves, no self/aug; P via popcount at the end
      #pragma unroll
      for (int nt = 0; nt < 8; ++nt) {
        const int bitpos = (nt & 1) * 16 + col;
        #pragma unroll
        for (int reg = 0; reg < 4; ++reg) {
          const unsigned int w = ((const unsigned int*)&pw[reg])[nt >> 1];
          const float d = acc[nt][reg];
          lacc[reg] += exp2f(fmaf(d, C_EXP, -C_EXP));
          if ((w >> bitpos) & 1) Sacc[reg] += d;
        }
      }
    } else {
      const bool left = (half == 0);
      #pragma unroll
      for (int nt = 0; nt < 8; ++nt) {
        const int joff = nt * 16 + col;
        const int jc = jbase + joff;
        const int bitpos = joff & 31;
        #pragma unroll
        for (int reg = 0; reg < 4; ++reg) {
          const int i = ibase + srow + quad * 4 + reg;
          const unsigned int w = ((const unsigned int*)&pw[reg])[nt >> 1];
          const float d = acc[nt][reg];
          const bool bit = (w >> bitpos) & 1;
          const bool self = left && (jc == i);
          const bool pos = left ? (bit && !self) : (bit || (jc == i));
          const float e = exp2f(fmaf(d, C_EXP, -C_EXP));
          if (!self) lacc[reg] += e;
          if (pos) { Sacc[reg] += d; Pcnt[reg] += 1.0f; }
        }
      }
    }
  }

  // ---- reduce across the 16 col-lanes, atomically accumulate per-anchor ----
  #pragma unroll
  for (int reg = 0; reg < 4; ++reg) {
    float l = lacc[reg], S = Sacc[reg], P = Pcnt[reg];
    #pragma unroll
    for (int m = 1; m < 16; m <<= 1) {
      l += __shfl_xor(l, m);
      S += __shfl_xor(S, m);
      if (diag) P += __shfl_xor(P, m);
    }
    if (col == 0) {
      const int i = ibase + srow + quad * 4 + reg;
      if (!diag) {
        const uint4 w = pw[reg];
        P = 2.0f * (float)(__popc(w.x) + __popc(w.y) + __popc(w.z) + __popc(w.w));
      }
      atomicAdd(&part[i], l);
      atomicAdd(&part[4096 + i], S);
      atomicAdd(&part[8192 + i], P);
    }
  }
}

// ---------------- kernel 3: per-anchor loss + atomic final reduce ----------------
__global__ __launch_bounds__(128) void k_loss(
    const float* __restrict__ part, float* __restrict__ out)
{
  const int a = blockIdx.x * 128 + threadIdx.x;   // 0..4095
  const float l = part[a];
  const float S = part[4096 + a];
  const float P = part[8192 + a];
  const float np = fmaxf(P, 1.0f);
  float v = INV_TAU + logf(l + 1e-8f) - (S * INV_TAU) / np;
  #pragma unroll
  for (int off = 32; off > 0; off >>= 1) v += __shfl_xor(v, off);
  __shared__ float ws2[2];
  const int wave = threadIdx.x >> 6, lane = threadIdx.x & 63;
  if (lane == 0) ws2[wave] = v;
  __syncthreads();
  if (threadIdx.x == 0) atomicAdd(out, (ws2[0] + ws2[1]) * (1.0f / (float)N_ROWS));
}

extern "C" void kernel_launch(void* const* d_in, const int* in_sizes, int n_in,
                              void* d_out, int out_size, void* d_ws, size_t ws_size,
                              hipStream_t stream) {
  const float* z1 = (const float*)d_in[0];
  const float* z2 = (const float*)d_in[1];
  const int* labels = (const int*)d_in[2];
  float* out = (float*)d_out;
  char* ws = (char*)d_ws;

  unsigned int* zbf    = (unsigned int*)(ws);
  uint2* labs8         = (uint2*)(ws + 2097152);
  int* s               = (int*)(ws + 4194304);
  float* part          = (float*)(ws + 4210688);
  unsigned int* pm     = (unsigned int*)(ws + 4259840);

  hipLaunchKernelGGL(k_norm_pack, dim3(2048), dim3(256), 0, stream,
                     z1, z2, labels, zbf, labs8, s, part, out);
  hipLaunchKernelGGL(k_jac, dim3(2080), dim3(128), 0, stream,
                     (const unsigned char*)labs8, s, pm);
  hipLaunchKernelGGL(k_fused, dim3(32, 32), dim3(512), 0, stream,
                     pm, (const unsigned short*)zbf, part);
  hipLaunchKernelGGL(k_loss, dim3(32), dim3(128), 0, stream, part, out);
}